// Round 11
// baseline (531.503 us; speedup 1.0000x reference)
//
#include <hip/hip_runtime.h>

#define NN 50000
#define NE 1600000
#define CLAMP_V 5.0f
#define SCAN_BLK 1024
#define NSCAN ((NN + SCAN_BLK - 1) / SCAN_BLK)   // 49

typedef __attribute__((ext_vector_type(4))) short bf16x4;
typedef __attribute__((ext_vector_type(4))) float f32x4;

static __device__ __forceinline__ short f2bf(float x) {
    unsigned u = __builtin_bit_cast(unsigned, x);
    u += 0x7FFF + ((u >> 16) & 1);   // round-to-nearest-even
    return (short)(u >> 16);
}

__global__ __launch_bounds__(256) void proj_kernel(
    const float* __restrict__ x,
    const float* __restrict__ WQ, const float* __restrict__ bQ,
    const float* __restrict__ WK, const float* __restrict__ WVw,
    float* __restrict__ Q, float* __restrict__ K, float* __restrict__ V)
{
    __shared__ float sWQ[4096], sWK[4096], sWV[4096];
    for (int i = threadIdx.x; i < 4096; i += 256) {
        sWQ[i] = WQ[i]; sWK[i] = WK[i]; sWV[i] = WVw[i];
    }
    __syncthreads();
    const int col = threadIdx.x & 63;
    const int nl  = threadIdx.x >> 6;
    const float bq = bQ[col];
    for (int node = blockIdx.x * 4 + nl; node < NN; node += gridDim.x * 4) {
        const float* xr = x + (size_t)node * 64;
        float aq = 0.f, ak = 0.f, av = 0.f;
        #pragma unroll
        for (int j = 0; j < 64; ++j) {
            float xv = xr[j];
            aq = fmaf(xv, sWQ[j*64+col], aq);
            ak = fmaf(xv, sWK[j*64+col], ak);
            av = fmaf(xv, sWV[j*64+col], av);
        }
        Q[(size_t)node*64+col] = aq + bq;
        K[(size_t)node*64+col] = ak;
        V[(size_t)node*64+col] = av;
    }
}

// ---------------- counting sort by dst (fast multi-block scan) --------------
__global__ __launch_bounds__(256) void hist_kernel(
    const int* __restrict__ ei, int* __restrict__ counts)
{
    for (int e = blockIdx.x * 256 + threadIdx.x; e < NE; e += gridDim.x * 256)
        atomicAdd(&counts[ei[NE + e]], 1);
}

__global__ __launch_bounds__(SCAN_BLK) void scan1_kernel(
    const int* __restrict__ counts, int* __restrict__ localEx,
    int* __restrict__ blockSum)
{
    __shared__ int buf[SCAN_BLK];
    const int i = blockIdx.x * SCAN_BLK + threadIdx.x;
    int v = (i < NN) ? counts[i] : 0;
    buf[threadIdx.x] = v;
    __syncthreads();
    for (int d = 1; d < SCAN_BLK; d <<= 1) {
        int t = (threadIdx.x >= d) ? buf[threadIdx.x - d] : 0;
        __syncthreads();
        buf[threadIdx.x] += t;
        __syncthreads();
    }
    if (i < NN) localEx[i] = buf[threadIdx.x] - v;
    if (threadIdx.x == SCAN_BLK - 1) blockSum[blockIdx.x] = buf[SCAN_BLK - 1];
}

__global__ __launch_bounds__(64) void scan2_kernel(
    const int* __restrict__ blockSum, int* __restrict__ blockOff)
{
    const int lane = threadIdx.x;
    int v = (lane < NSCAN) ? blockSum[lane] : 0;
    int incl = v;
    #pragma unroll
    for (int d = 1; d < 64; d <<= 1) {
        int t = __shfl_up(incl, d);
        if (lane >= d) incl += t;
    }
    if (lane < NSCAN) blockOff[lane] = incl - v;
}

__global__ __launch_bounds__(SCAN_BLK) void scan3_kernel(
    const int* __restrict__ localEx, const int* __restrict__ blockOff,
    int* __restrict__ cursor)
{
    const int i = blockIdx.x * SCAN_BLK + threadIdx.x;
    if (i < NN) cursor[i] = localEx[i] + blockOff[blockIdx.x];
}

__global__ __launch_bounds__(256) void scatter_kernel(
    const int* __restrict__ ei, int* __restrict__ cursor,
    int* __restrict__ sortedE, int2* __restrict__ sortedSD)
{
    for (int e = blockIdx.x * 256 + threadIdx.x; e < NE; e += gridDim.x * 256) {
        const int src = ei[e], dst = ei[NE + e];
        const int pos = atomicAdd(&cursor[dst], 1);
        sortedE[pos]  = e;
        sortedSD[pos] = make_int2(src, dst);
    }
}

// ---------------- fused edge pass over dst-sorted edges --------------------
// E = edge_attr@WE1+bE1 (MFMA), sc = K[src]*Q[dst]*E -> wE[eid],
// ex = exp(clamp(sum_head/sqrt8)).  Sorted dst => segmented register
// accumulation; ONE f32 atomic flush per dst-run per wave-tile (~1.5/tile)
// instead of per-edge atomics.
__global__ __launch_bounds__(256) void edge_fused_kernel(
    const float* __restrict__ edge_attr,
    const float* __restrict__ WE1, const float* __restrict__ bE1,
    const int* __restrict__ sortedE, const int2* __restrict__ sortedSD,
    const float* __restrict__ Q, const float* __restrict__ K,
    const float* __restrict__ V,
    float* __restrict__ wE, float* __restrict__ den, float* __restrict__ Num)
{
    __shared__ float Elds[4][16 * 64];   // [wave][edge][col]: E, then P in-place
    __shared__ float exL[4][16 * 8];     // [wave][edge][head] ex
    __shared__ int   dstL[4][16];        // [wave][edge] dst (sorted, nondecreasing)
    const int tid  = threadIdx.x;
    const int wv   = tid >> 6;
    const int lane = tid & 63;
    const int g    = lane >> 4;      // k-group (MFMA) / edge-in-quad (scoring)
    const int rowl = lane & 15;      // A-row (MFMA) / col-quad (scoring)

    // B fragments of WE1 (bf16) + bias. B[k=(ks*16 + g*4 + j)][col]
    bf16x4 bF[4][4];
    float  bias[4];
    #pragma unroll
    for (int cb = 0; cb < 4; ++cb) {
        const int col = rowl + 16 * cb;
        bias[cb] = bE1[col];
        #pragma unroll
        for (int ks = 0; ks < 4; ++ks) {
            bf16x4 t;
            #pragma unroll
            for (int j = 0; j < 4; ++j)
                t[j] = f2bf(WE1[(ks * 16 + g * 4 + j) * 64 + col]);
            bF[cb][ks] = t;
        }
    }

    const float inv_sqrt8 = 0.35355339059327373f;

    for (int tile = blockIdx.x; tile < (NE / 64); tile += gridDim.x) {
        const int pBase = tile * 64 + wv * 16;   // position in sorted order

        const int2 sdv  = sortedSD[pBase + rowl];
        const int  eidv = sortedE[pBase + rowl];
        const int  srcv = sdv.x, dstv = sdv.y;
        if (lane < 16) dstL[wv][lane] = dstv;

        // A fragments: edge_attr[eid][ks*16 + g*4 + j] (nontemporal gather)
        bf16x4 aF[4];
        const float* ar = edge_attr + (size_t)eidv * 64 + g * 4;
        #pragma unroll
        for (int ks = 0; ks < 4; ++ks) {
            f32x4 v = __builtin_nontemporal_load(
                reinterpret_cast<const f32x4*>(ar + ks * 16));
            bf16x4 t;
            #pragma unroll
            for (int j = 0; j < 4; ++j) t[j] = f2bf(v[j]);
            aF[ks] = t;
        }

        f32x4 acc[4];
        #pragma unroll
        for (int cb = 0; cb < 4; ++cb) {
            acc[cb][0] = bias[cb]; acc[cb][1] = bias[cb];
            acc[cb][2] = bias[cb]; acc[cb][3] = bias[cb];
        }
        #pragma unroll
        for (int cb = 0; cb < 4; ++cb)
            #pragma unroll
            for (int ks = 0; ks < 4; ++ks)
                acc[cb] = __builtin_amdgcn_mfma_f32_16x16x16bf16_1k(
                    aF[ks], bF[cb][ks], acc[cb], 0, 0, 0);

        // D layout: row=(lane>>4)*4+r, col=(lane&15)+16*cb  -> LDS transpose
        #pragma unroll
        for (int cb = 0; cb < 4; ++cb)
            #pragma unroll
            for (int r = 0; r < 4; ++r)
                Elds[wv][(g * 4 + r) * 64 + rowl + 16 * cb] = acc[cb][r];

        // Scoring: 4 edges in parallel, float4 per lane; P overwrites E in LDS
        #pragma unroll
        for (int qi = 0; qi < 4; ++qi) {
            const int el  = qi * 4 + g;
            const int eid = __shfl(eidv, el);
            const int src = __shfl(srcv, el);
            const int dst = __shfl(dstv, el);
            const f32x4 Kv = *reinterpret_cast<const f32x4*>(K + (size_t)src * 64 + rowl * 4);
            const f32x4 Qv = *reinterpret_cast<const f32x4*>(Q + (size_t)dst * 64 + rowl * 4);
            const f32x4 Vv = *reinterpret_cast<const f32x4*>(V + (size_t)src * 64 + rowl * 4);
            f32x4* eslot = reinterpret_cast<f32x4*>(&Elds[wv][el * 64 + rowl * 4]);
            const f32x4 El = *eslot;
            f32x4 sc;
            #pragma unroll
            for (int j = 0; j < 4; ++j) sc[j] = Kv[j] * Qv[j] * El[j];
            __builtin_nontemporal_store(sc,
                reinterpret_cast<f32x4*>(wE + (size_t)eid * 64 + rowl * 4));
            float ss = sc[0] + sc[1] + sc[2] + sc[3];
            ss += __shfl_xor(ss, 1);          // head sum (8 cols)
            float s = fminf(fmaxf(ss * inv_sqrt8, -CLAMP_V), CLAMP_V);
            float ex = __expf(s);
            if ((rowl & 1) == 0)
                exL[wv][el * 8 + (rowl >> 1)] = ex;
            f32x4 t;
            #pragma unroll
            for (int j = 0; j < 4; ++j) t[j] = ex * (Vv[j] + sc[j]);
            *eslot = t;                        // P in-place over E
        }

        // Segmented accumulation over sorted dst; flush once per run.
        float accP = 0.f, accD = 0.f;
        int cur = dstL[wv][0];
        #pragma unroll
        for (int el = 0; el < 16; ++el) {
            accP += Elds[wv][el * 64 + lane];
            accD += exL[wv][el * 8 + (lane & 7)];
            const int nxt = (el < 15) ? dstL[wv][el + 1] : -1;
            if (nxt != cur) {                  // wave-uniform
                atomicAdd(&Num[(size_t)cur * 64 + lane], accP);
                if (lane < 8) atomicAdd(&den[cur * 8 + lane], accD);
                accP = 0.f; accD = 0.f; cur = nxt;
            }
        }
    }
}

__global__ __launch_bounds__(256) void finalize_kernel(
    const float* __restrict__ Num, const float* __restrict__ den,
    float* __restrict__ wV)
{
    const int i = blockIdx.x * 256 + threadIdx.x;   // one float4 per thread
    if (i >= NN * 16) return;
    const int c4 = i & 15;
    const int n  = i >> 4;
    const int h  = c4 >> 1;
    const float d = den[n * 8 + h] + 1e-16f;
    f32x4 v = reinterpret_cast<const f32x4*>(Num)[i];
    v[0] /= d; v[1] /= d; v[2] /= d; v[3] /= d;
    reinterpret_cast<f32x4*>(wV)[i] = v;
}

extern "C" void kernel_launch(void* const* d_in, const int* in_sizes, int n_in,
                              void* d_out, int out_size, void* d_ws, size_t ws_size,
                              hipStream_t stream) {
    const float* x         = (const float*)d_in[0];
    const float* edge_attr = (const float*)d_in[1];
    const float* WQ        = (const float*)d_in[2];
    const float* bQ        = (const float*)d_in[3];
    const float* WK        = (const float*)d_in[4];
    const float* WVw       = (const float*)d_in[5];
    const float* WE1       = (const float*)d_in[6];
    const float* bE1       = (const float*)d_in[7];
    const int*   ei        = (const int*)d_in[8];

    float* out = (float*)d_out;
    float* wV = out;                          // [NN, 64]
    float* wE = out + (size_t)NN * 64;        // [NE, 64]

    float* Q        = (float*)d_ws;                    // [NN,64]
    float* K        = Q + (size_t)NN * 64;             // [NN,64]
    float* V        = K + (size_t)NN * 64;             // [NN,64]
    float* den      = V + (size_t)NN * 64;             // [NN,8]
    float* Num      = den + (size_t)NN * 8;            // [NN,64]
    int*   counts   = (int*)(Num + (size_t)NN * 64);   // [NN]
    int*   localEx  = counts + NN;                     // [NN]
    int*   blockSum = localEx + NN;                    // [64]
    int*   blockOff = blockSum + 64;                   // [64]
    int*   cursor   = blockOff + 64;                   // [NN]
    int*   sortedE  = cursor + NN;                     // [NE]
    int2*  sortedSD = (int2*)(sortedE + NE);           // [NE]

    hipMemsetAsync(counts, 0, (size_t)NN * sizeof(int), stream);
    hipMemsetAsync(den, 0, (size_t)NN * (8 + 64) * sizeof(float), stream);

    hist_kernel<<<1024, 256, 0, stream>>>(ei, counts);
    scan1_kernel<<<NSCAN, SCAN_BLK, 0, stream>>>(counts, localEx, blockSum);
    scan2_kernel<<<1, 64, 0, stream>>>(blockSum, blockOff);
    scan3_kernel<<<NSCAN, SCAN_BLK, 0, stream>>>(localEx, blockOff, cursor);
    scatter_kernel<<<1024, 256, 0, stream>>>(ei, cursor, sortedE, sortedSD);
    proj_kernel<<<2048, 256, 0, stream>>>(x, WQ, bQ, WK, WVw, Q, K, V);
    edge_fused_kernel<<<2048, 256, 0, stream>>>(edge_attr, WE1, bE1,
                                                sortedE, sortedSD,
                                                Q, K, V, wE, den, Num);
    finalize_kernel<<<(NN * 16 + 255) / 256, 256, 0, stream>>>(Num, den, wV);
}

// Round 12
// 354.524 us; speedup vs baseline: 1.4992x; 1.4992x over previous
//
#include <hip/hip_runtime.h>

#define NN 50000
#define NE 1600000
#define CLAMP_V 5.0f
#define NB 2048                    // phase-1 chunks
#define CH ((NE + NB - 1) / NB)    // 782 edges per chunk
#define BSHIFT 9                   // 512 nodes per bucket
#define NBUCK ((NN + (1 << BSHIFT) - 1) >> BSHIFT)   // 98
#define BPAD 128                   // padded bucket slot per block

typedef __attribute__((ext_vector_type(4))) short bf16x4;
typedef __attribute__((ext_vector_type(4))) float f32x4;

static __device__ __forceinline__ short f2bf(float x) {
    unsigned u = __builtin_bit_cast(unsigned, x);
    u += 0x7FFF + ((u >> 16) & 1);   // round-to-nearest-even
    return (short)(u >> 16);
}

__global__ __launch_bounds__(256) void proj_kernel(
    const float* __restrict__ x,
    const float* __restrict__ WQ, const float* __restrict__ bQ,
    const float* __restrict__ WK, const float* __restrict__ WVw,
    float* __restrict__ Q, float* __restrict__ K, float* __restrict__ V)
{
    __shared__ float sWQ[4096], sWK[4096], sWV[4096];
    for (int i = threadIdx.x; i < 4096; i += 256) {
        sWQ[i] = WQ[i]; sWK[i] = WK[i]; sWV[i] = WVw[i];
    }
    __syncthreads();
    const int col = threadIdx.x & 63;
    const int nl  = threadIdx.x >> 6;
    const float bq = bQ[col];
    for (int node = blockIdx.x * 4 + nl; node < NN; node += gridDim.x * 4) {
        const float* xr = x + (size_t)node * 64;
        float aq = 0.f, ak = 0.f, av = 0.f;
        #pragma unroll
        for (int j = 0; j < 64; ++j) {
            float xv = xr[j];
            aq = fmaf(xv, sWQ[j*64+col], aq);
            ak = fmaf(xv, sWK[j*64+col], ak);
            av = fmaf(xv, sWV[j*64+col], av);
        }
        Q[(size_t)node*64+col] = aq + bq;
        K[(size_t)node*64+col] = ak;
        V[(size_t)node*64+col] = av;
    }
}

// ---------- phase 1: coarse bin by dst>>9 (R9-style, LDS hist/cursors) ------
__global__ __launch_bounds__(256) void hist1_kernel(
    const int* __restrict__ ei, int* __restrict__ blockHist)
{
    __shared__ int h[BPAD];
    if (threadIdx.x < BPAD) h[threadIdx.x] = 0;
    __syncthreads();
    const int b  = blockIdx.x;
    const int e0 = b * CH;
    const int e1 = (e0 + CH < NE) ? e0 + CH : NE;
    for (int e = e0 + threadIdx.x; e < e1; e += 256)
        atomicAdd(&h[ei[NE + e] >> BSHIFT], 1);
    __syncthreads();
    if (threadIdx.x < NBUCK) blockHist[b * BPAD + threadIdx.x] = h[threadIdx.x];
}

// one wave per bucket: in-place exclusive scan over the 2048 chunk counts
__global__ __launch_bounds__(64) void scanA_kernel(
    int* __restrict__ blockHist, int* __restrict__ bucketTotal)
{
    const int k    = blockIdx.x;
    const int lane = threadIdx.x;
    int running = 0;
    for (int c = 0; c < NB; c += 64) {
        int v = blockHist[(c + lane) * BPAD + k];
        int incl = v;
        #pragma unroll
        for (int d = 1; d < 64; d <<= 1) {
            int t = __shfl_up(incl, d);
            if (lane >= d) incl += t;
        }
        blockHist[(c + lane) * BPAD + k] = running + (incl - v);
        running += __shfl(incl, 63);
    }
    if (lane == 0) bucketTotal[k] = running;
}

__global__ void scanB_kernel(const int* __restrict__ bucketTotal,
                             int* __restrict__ bucketStart)
{
    int acc = 0;
    for (int k = 0; k < NBUCK; ++k) { bucketStart[k] = acc; acc += bucketTotal[k]; }
    bucketStart[NBUCK] = acc;   // == NE
}

__global__ __launch_bounds__(256) void scatter1_kernel(
    const int* __restrict__ ei, const int* __restrict__ blockHist,
    const int* __restrict__ bucketStart, uint2* __restrict__ binned)
{
    __shared__ int cur[BPAD];
    const int b = blockIdx.x;
    if (threadIdx.x < NBUCK)
        cur[threadIdx.x] = bucketStart[threadIdx.x] + blockHist[b * BPAD + threadIdx.x];
    __syncthreads();
    const int e0 = b * CH;
    const int e1 = (e0 + CH < NE) ? e0 + CH : NE;
    for (int e = e0 + threadIdx.x; e < e1; e += 256) {
        const unsigned src = ei[e], dst = ei[NE + e];
        const int pos = atomicAdd(&cur[dst >> BSHIFT], 1);
        binned[pos] = make_uint2((dst << 16) | src, (unsigned)e);
    }
}

// ---------- phase 2: per-bucket counting sort (L2-local window) -------------
__global__ __launch_bounds__(1024) void sort2_kernel(
    const uint2* __restrict__ binned, const int* __restrict__ bucketStart,
    uint2* __restrict__ sorted)
{
    __shared__ int cnt[512];
    __shared__ int pre[512];
    const int b  = blockIdx.x;
    const int lo = bucketStart[b];
    const int hi = bucketStart[b + 1];
    if (threadIdx.x < 512) cnt[threadIdx.x] = 0;
    __syncthreads();
    for (int p = lo + threadIdx.x; p < hi; p += 1024)
        atomicAdd(&cnt[(binned[p].x >> 16) & 511], 1);
    __syncthreads();
    if (threadIdx.x < 512) pre[threadIdx.x] = cnt[threadIdx.x];
    __syncthreads();
    for (int d = 1; d < 512; d <<= 1) {
        int t = (threadIdx.x < 512 && threadIdx.x >= d) ? pre[threadIdx.x - d] : 0;
        __syncthreads();
        if (threadIdx.x < 512) pre[threadIdx.x] += t;
        __syncthreads();
    }
    if (threadIdx.x < 512)
        cnt[threadIdx.x] = lo + pre[threadIdx.x] - cnt[threadIdx.x];  // exclusive cursor
    __syncthreads();
    for (int p = lo + threadIdx.x; p < hi; p += 1024) {
        const uint2 q = binned[p];
        const int pos = atomicAdd(&cnt[(q.x >> 16) & 511], 1);
        sorted[pos] = q;
    }
}

// ---------- fused edge pass over fully dst-sorted edges ---------------------
__global__ __launch_bounds__(256) void edge_fused_kernel(
    const float* __restrict__ edge_attr,
    const float* __restrict__ WE1, const float* __restrict__ bE1,
    const uint2* __restrict__ sorted,
    const float* __restrict__ Q, const float* __restrict__ K,
    const float* __restrict__ V,
    float* __restrict__ wE, float* __restrict__ den, float* __restrict__ Num)
{
    __shared__ float Elds[4][16 * 64];   // [wave][edge][col]: E, then P in-place
    __shared__ float exL[4][16 * 8];     // [wave][edge][head] ex
    __shared__ int   dstL[4][16];        // [wave][edge] dst (nondecreasing)
    const int tid  = threadIdx.x;
    const int wv   = tid >> 6;
    const int lane = tid & 63;
    const int g    = lane >> 4;
    const int rowl = lane & 15;

    bf16x4 bF[4][4];
    float  bias[4];
    #pragma unroll
    for (int cb = 0; cb < 4; ++cb) {
        const int col = rowl + 16 * cb;
        bias[cb] = bE1[col];
        #pragma unroll
        for (int ks = 0; ks < 4; ++ks) {
            bf16x4 t;
            #pragma unroll
            for (int j = 0; j < 4; ++j)
                t[j] = f2bf(WE1[(ks * 16 + g * 4 + j) * 64 + col]);
            bF[cb][ks] = t;
        }
    }

    const float inv_sqrt8 = 0.35355339059327373f;

    for (int tile = blockIdx.x; tile < (NE / 64); tile += gridDim.x) {
        const int pBase = tile * 64 + wv * 16;

        const uint2 qv  = sorted[pBase + rowl];
        const int  srcv = qv.x & 0xffff;
        const int  dstv = qv.x >> 16;
        const int  eidv = (int)qv.y;
        if (lane < 16) dstL[wv][lane] = dstv;

        bf16x4 aF[4];
        const float* ar = edge_attr + (size_t)eidv * 64 + g * 4;
        #pragma unroll
        for (int ks = 0; ks < 4; ++ks) {
            f32x4 v = __builtin_nontemporal_load(
                reinterpret_cast<const f32x4*>(ar + ks * 16));
            bf16x4 t;
            #pragma unroll
            for (int j = 0; j < 4; ++j) t[j] = f2bf(v[j]);
            aF[ks] = t;
        }

        f32x4 acc[4];
        #pragma unroll
        for (int cb = 0; cb < 4; ++cb) {
            acc[cb][0] = bias[cb]; acc[cb][1] = bias[cb];
            acc[cb][2] = bias[cb]; acc[cb][3] = bias[cb];
        }
        #pragma unroll
        for (int cb = 0; cb < 4; ++cb)
            #pragma unroll
            for (int ks = 0; ks < 4; ++ks)
                acc[cb] = __builtin_amdgcn_mfma_f32_16x16x16bf16_1k(
                    aF[ks], bF[cb][ks], acc[cb], 0, 0, 0);

        #pragma unroll
        for (int cb = 0; cb < 4; ++cb)
            #pragma unroll
            for (int r = 0; r < 4; ++r)
                Elds[wv][(g * 4 + r) * 64 + rowl + 16 * cb] = acc[cb][r];

        #pragma unroll
        for (int qi = 0; qi < 4; ++qi) {
            const int el  = qi * 4 + g;
            const int eid = __shfl(eidv, el);
            const int src = __shfl(srcv, el);
            const int dst = __shfl(dstv, el);
            const f32x4 Kv = *reinterpret_cast<const f32x4*>(K + (size_t)src * 64 + rowl * 4);
            const f32x4 Qv = *reinterpret_cast<const f32x4*>(Q + (size_t)dst * 64 + rowl * 4);
            const f32x4 Vv = *reinterpret_cast<const f32x4*>(V + (size_t)src * 64 + rowl * 4);
            f32x4* eslot = reinterpret_cast<f32x4*>(&Elds[wv][el * 64 + rowl * 4]);
            const f32x4 El = *eslot;
            f32x4 sc;
            #pragma unroll
            for (int j = 0; j < 4; ++j) sc[j] = Kv[j] * Qv[j] * El[j];
            __builtin_nontemporal_store(sc,
                reinterpret_cast<f32x4*>(wE + (size_t)eid * 64 + rowl * 4));
            float ss = sc[0] + sc[1] + sc[2] + sc[3];
            ss += __shfl_xor(ss, 1);
            float s = fminf(fmaxf(ss * inv_sqrt8, -CLAMP_V), CLAMP_V);
            float ex = __expf(s);
            if ((rowl & 1) == 0)
                exL[wv][el * 8 + (rowl >> 1)] = ex;
            f32x4 t;
            #pragma unroll
            for (int j = 0; j < 4; ++j) t[j] = ex * (Vv[j] + sc[j]);
            *eslot = t;
        }

        // segmented accumulation over sorted dst; one flush per run
        float accP = 0.f, accD = 0.f;
        int cur = dstL[wv][0];
        #pragma unroll
        for (int el = 0; el < 16; ++el) {
            accP += Elds[wv][el * 64 + lane];
            accD += exL[wv][el * 8 + (lane & 7)];
            const int nxt = (el < 15) ? dstL[wv][el + 1] : -1;
            if (nxt != cur) {
                atomicAdd(&Num[(size_t)cur * 64 + lane], accP);
                if (lane < 8) atomicAdd(&den[cur * 8 + lane], accD);
                accP = 0.f; accD = 0.f; cur = nxt;
            }
        }
    }
}

__global__ __launch_bounds__(256) void finalize_kernel(
    const float* __restrict__ Num, const float* __restrict__ den,
    float* __restrict__ wV)
{
    const int i = blockIdx.x * 256 + threadIdx.x;
    if (i >= NN * 16) return;
    const int c4 = i & 15;
    const int n  = i >> 4;
    const int h  = c4 >> 1;
    const float d = den[n * 8 + h] + 1e-16f;
    f32x4 v = reinterpret_cast<const f32x4*>(Num)[i];
    v[0] /= d; v[1] /= d; v[2] /= d; v[3] /= d;
    reinterpret_cast<f32x4*>(wV)[i] = v;
}

extern "C" void kernel_launch(void* const* d_in, const int* in_sizes, int n_in,
                              void* d_out, int out_size, void* d_ws, size_t ws_size,
                              hipStream_t stream) {
    const float* x         = (const float*)d_in[0];
    const float* edge_attr = (const float*)d_in[1];
    const float* WQ        = (const float*)d_in[2];
    const float* bQ        = (const float*)d_in[3];
    const float* WK        = (const float*)d_in[4];
    const float* WVw       = (const float*)d_in[5];
    const float* WE1       = (const float*)d_in[6];
    const float* bE1       = (const float*)d_in[7];
    const int*   ei        = (const int*)d_in[8];

    float* out = (float*)d_out;
    float* wV = out;                          // [NN, 64]
    float* wE = out + (size_t)NN * 64;        // [NE, 64]

    float* Q           = (float*)d_ws;                  // [NN,64]
    float* K           = Q + (size_t)NN * 64;           // [NN,64]
    float* V           = K + (size_t)NN * 64;           // [NN,64]
    float* den         = V + (size_t)NN * 64;           // [NN,8]
    float* Num         = den + (size_t)NN * 8;          // [NN,64]
    int*   blockHist   = (int*)(Num + (size_t)NN * 64); // [NB,BPAD]
    int*   bucketTotal = blockHist + NB * BPAD;         // [BPAD]
    int*   bucketStart = bucketTotal + BPAD;            // [BPAD]
    uint2* binned      = (uint2*)(bucketStart + BPAD);  // [NE]
    uint2* sorted      = binned + NE;                   // [NE]

    hipMemsetAsync(den, 0, (size_t)NN * (8 + 64) * sizeof(float), stream);

    hist1_kernel<<<NB, 256, 0, stream>>>(ei, blockHist);
    scanA_kernel<<<NBUCK, 64, 0, stream>>>(blockHist, bucketTotal);
    scanB_kernel<<<1, 1, 0, stream>>>(bucketTotal, bucketStart);
    scatter1_kernel<<<NB, 256, 0, stream>>>(ei, blockHist, bucketStart, binned);
    sort2_kernel<<<NBUCK, 1024, 0, stream>>>(binned, bucketStart, sorted);
    proj_kernel<<<1024, 256, 0, stream>>>(x, WQ, bQ, WK, WVw, Q, K, V);
    edge_fused_kernel<<<2048, 256, 0, stream>>>(edge_attr, WE1, bE1, sorted,
                                                Q, K, V, wE, den, Num);
    finalize_kernel<<<(NN * 16 + 255) / 256, 256, 0, stream>>>(Num, den, wV);
}